// Round 5
// baseline (600.211 us; speedup 1.0000x reference)
//
#include <hip/hip_runtime.h>

typedef __attribute__((ext_vector_type(8))) __bf16   bf16x8;
typedef __attribute__((ext_vector_type(8))) _Float16 f16x8;
typedef __attribute__((ext_vector_type(4))) float    f32x4;

#define MFMA_BF16 __builtin_amdgcn_mfma_f32_16x16x32_bf16
#define MFMA_F16  __builtin_amdgcn_mfma_f32_16x16x32_f16

__device__ __forceinline__ void split_bf16(float x, __bf16& h, __bf16& l) {
    h = (__bf16)x;
    l = (__bf16)(x - (float)h);
}

// ---------------------------------------------------------------------------
// One-time f32 -> (hi, lo) bf16 planes. n8 = n/8.
// ---------------------------------------------------------------------------
__global__ __launch_bounds__(256)
void split_kernel(const float* __restrict__ src, __bf16* __restrict__ hi,
                  __bf16* __restrict__ lo, int n8)
{
    int i = blockIdx.x * 256 + threadIdx.x;
    if (i >= n8) return;
    float4 v0 = *(const float4*)(src + (size_t)i * 8);
    float4 v1 = *(const float4*)(src + (size_t)i * 8 + 4);
    float xs[8] = {v0.x, v0.y, v0.z, v0.w, v1.x, v1.y, v1.z, v1.w};
    bf16x8 h8, l8;
    #pragma unroll
    for (int j = 0; j < 8; j++) { __bf16 h, l; split_bf16(xs[j], h, l); h8[j] = h; l8[j] = l; }
    *(bf16x8*)(hi + (size_t)i * 8) = h8;
    *(bf16x8*)(lo + (size_t)i * 8) = l8;
}

// ---------------------------------------------------------------------------
// Split-bf16 MFMA GEMM: C[M,N] = A[M,K] * B[N,K]^T with A,B in (hi,lo) planes.
// 3 MFMAs (hh + lh + hl) ~ f32 accuracy. 128x128 tile, BK=32, 256 thr, 4 waves
// (2x2), 64x64 per wave. LDS pitch 40 bf16 (80 B) -> conflict-free b128 reads.
// MODE 0: f32 C.  MODE 1: split (hi,lo) C with scale.  MODE 2: f16 C.
// ---------------------------------------------------------------------------
template<int MODE>
__global__ __launch_bounds__(256, 4)
void gemm_split(const __bf16* __restrict__ Ahg, const __bf16* __restrict__ Alg,
                const __bf16* __restrict__ Bhg, const __bf16* __restrict__ Blg,
                float* __restrict__ Cf, __bf16* __restrict__ Chi,
                __bf16* __restrict__ Clo, _Float16* __restrict__ Ch,
                int M, int N, int K, float scale)
{
    const int P = 40;
    __shared__ __bf16 Ah[128][P], Al[128][P], Bh[128][P], Bl[128][P];

    const int t   = threadIdx.x;
    const int lane = t & 63;
    const int wid  = t >> 6;
    const int l15  = lane & 15;
    const int lg   = lane >> 4;
    const int wr   = wid >> 1, wc = wid & 1;
    const int m0 = blockIdx.x * 128, n0 = blockIdx.y * 128;

    f32x4 acc[4][4];
    #pragma unroll
    for (int i = 0; i < 4; i++)
        #pragma unroll
        for (int j = 0; j < 4; j++)
            #pragma unroll
            for (int r = 0; r < 4; r++) acc[i][j][r] = 0.f;

    for (int k0 = 0; k0 < K; k0 += 32) {
        __syncthreads();
        #pragma unroll
        for (int i = 0; i < 2; i++) {
            int id = t + 256 * i;
            int row = id >> 2, cc = id & 3;
            size_t ga = (size_t)(m0 + row) * K + k0 + cc * 8;
            size_t gb = (size_t)(n0 + row) * K + k0 + cc * 8;
            *(bf16x8*)&Ah[row][cc*8] = *(const bf16x8*)(Ahg + ga);
            *(bf16x8*)&Al[row][cc*8] = *(const bf16x8*)(Alg + ga);
            *(bf16x8*)&Bh[row][cc*8] = *(const bf16x8*)(Bhg + gb);
            *(bf16x8*)&Bl[row][cc*8] = *(const bf16x8*)(Blg + gb);
        }
        __syncthreads();

        bf16x8 ah[4], al[4];
        #pragma unroll
        for (int mr = 0; mr < 4; mr++) {
            ah[mr] = *(const bf16x8*)&Ah[wr*64 + mr*16 + l15][lg*8];
            al[mr] = *(const bf16x8*)&Al[wr*64 + mr*16 + l15][lg*8];
        }
        #pragma unroll
        for (int nr = 0; nr < 4; nr++) {
            bf16x8 bh = *(const bf16x8*)&Bh[wc*64 + nr*16 + l15][lg*8];
            bf16x8 bl = *(const bf16x8*)&Bl[wc*64 + nr*16 + l15][lg*8];
            #pragma unroll
            for (int mr = 0; mr < 4; mr++) {
                acc[mr][nr] = MFMA_BF16(ah[mr], bh, acc[mr][nr], 0, 0, 0);
                acc[mr][nr] = MFMA_BF16(al[mr], bh, acc[mr][nr], 0, 0, 0);
                acc[mr][nr] = MFMA_BF16(ah[mr], bl, acc[mr][nr], 0, 0, 0);
            }
        }
    }

    #pragma unroll
    for (int mr = 0; mr < 4; mr++)
    #pragma unroll
    for (int r = 0; r < 4; r++) {
        int row = m0 + wr*64 + mr*16 + lg*4 + r;
        #pragma unroll
        for (int nr = 0; nr < 4; nr++) {
            int col = n0 + wc*64 + nr*16 + l15;
            float v = acc[mr][nr][r] * scale;
            if constexpr (MODE == 0) {
                Cf[(size_t)row * N + col] = v;
            } else if constexpr (MODE == 1) {
                __bf16 h, l; split_bf16(v, h, l);
                Chi[(size_t)row * N + col] = h;
                Clo[(size_t)row * N + col] = l;
            } else {
                Ch[(size_t)row * N + col] = (_Float16)v;
            }
        }
    }
}

// ---------------------------------------------------------------------------
// MFMA flash attention on pre-split inputs. Block = 256 q-rows x one (b,h),
// 1024 thr = 16 waves x 16 q-rows. KV tile 64, Dk 64.
//  - Register prefetch of next K/V tile: global latency hides under compute.
//  - Q/K hi+lo bf16 (pre-split; Q pre-scaled by 1/8) -> 3-MFMA QK^T.
//  - V^T in LDS, column-block XOR swizzle (writes+reads conflict-free).
//  - Ps column-block swizzle c8 ^= (row>>1)&7: scalar P writes 2-way (free),
//    b128 reads stay contiguous.
//  - Rescale-skip: wave-uniform __any(new max) gate; skipped corr == 1.0
//    exactly, so results are bit-identical.
//  - XCD-clustered flat grid; AO (hi,lo) via LDS bounce, 16B stores.
// ---------------------------------------------------------------------------
__global__ __launch_bounds__(1024, 4)
void attn_mfma(const __bf16* __restrict__ Qh_g, const __bf16* __restrict__ Ql_g,
               const __bf16* __restrict__ Kh_g, const __bf16* __restrict__ Kl_g,
               const _Float16* __restrict__ Vh_g, const int* __restrict__ mask,
               __bf16* AOh, __bf16* AOl)
{
    const int S = 2048, E = 1024;
    __shared__ __bf16   Khi[64][72];
    __shared__ __bf16   Klo[64][72];
    __shared__ _Float16 Vt[64][72];
    __shared__ _Float16 Ps[256][72];

    const int tid  = threadIdx.x;
    const int lane = tid & 63;
    const int wid  = tid >> 6;          // 0..15
    const int l15  = lane & 15;
    const int lg   = lane >> 4;

    // XCD-clustered decode: fid -> (qb, h, b)
    const int fid = blockIdx.x;         // 0..511
    const int xcd = fid & 7;
    const int j   = fid >> 3;           // 0..63
    const int bh  = xcd * 8 + (j >> 3); // 0..63
    const int qb  = j & 7;
    const int h   = bh & 15;
    const int b   = bh >> 4;
    const int q0  = qb * 256;
    const size_t base = (size_t)b * S * E + (size_t)h * 64;

    // Q fragments (already scaled by 1/8 and split)
    bf16x8 qh[2], ql[2];
    {
        size_t qoff = base + (size_t)(q0 + wid*16 + l15) * E;
        #pragma unroll
        for (int kc = 0; kc < 2; kc++) {
            qh[kc] = *(const bf16x8*)(Qh_g + qoff + kc*32 + lg*8);
            ql[kc] = *(const bf16x8*)(Ql_g + qoff + kc*32 + lg*8);
        }
    }

    f32x4 o[4];
    #pragma unroll
    for (int nt = 0; nt < 4; nt++)
        #pragma unroll
        for (int r = 0; r < 4; r++) o[nt][r] = 0.f;
    float mrow[4], lrow[4];
    #pragma unroll
    for (int r = 0; r < 4; r++) { mrow[r] = -1e30f; lrow[r] = 0.f; }

    // staging role (wave-uniform split: waves 0-7 stage K, 8-15 stage V)
    const bool isK = tid < 512;
    const int  srow = (tid & 511) >> 3;   // 0..63
    const int  scc  = tid & 7;            // 0..7

    // prefetch tile 0 into registers
    bf16x8 kh_r, kl_r; f16x8 v_r;
    {
        size_t g0 = base + (size_t)srow * E + scc * 8;
        if (isK) { kh_r = *(const bf16x8*)(Kh_g + g0);
                   kl_r = *(const bf16x8*)(Kl_g + g0); }
        else     { v_r  = *(const f16x8*)(Vh_g + g0); }
    }

    const int NT = S / 64;                // 32
    for (int t = 0; t < NT; t++) {
        const int k0 = t * 64;
        __syncthreads();   // previous iteration's LDS reads done

        // write prefetched tile to LDS
        if (isK) {
            *(bf16x8*)&Khi[srow][scc*8] = kh_r;
            *(bf16x8*)&Klo[srow][scc*8] = kl_r;
        } else {
            int cbase = ((srow >> 3) ^ scc) * 8 + (srow & 7);
            #pragma unroll
            for (int jj = 0; jj < 8; jj++)
                Vt[scc*8 + jj][cbase] = v_r[jj];
        }

        // issue next tile's global loads (clamped; overlap with compute)
        {
            int tn = (t + 1 < NT) ? t + 1 : NT - 1;
            size_t gn = base + (size_t)(tn*64 + srow) * E + scc * 8;
            if (isK) { kh_r = *(const bf16x8*)(Kh_g + gn);
                       kl_r = *(const bf16x8*)(Kl_g + gn); }
            else     { v_r  = *(const f16x8*)(Vh_g + gn); }
        }
        __syncthreads();

        // S = Q K^T (hh + lh + hl)
        f32x4 sf[4];
        #pragma unroll
        for (int nt = 0; nt < 4; nt++)
            #pragma unroll
            for (int r = 0; r < 4; r++) sf[nt][r] = 0.f;

        __builtin_amdgcn_s_setprio(1);
        #pragma unroll
        for (int kc = 0; kc < 2; kc++)
            #pragma unroll
            for (int nt = 0; nt < 4; nt++) {
                bf16x8 kbh = *(const bf16x8*)&Khi[nt*16 + l15][kc*32 + lg*8];
                bf16x8 kbl = *(const bf16x8*)&Klo[nt*16 + l15][kc*32 + lg*8];
                sf[nt] = MFMA_BF16(qh[kc], kbh, sf[nt], 0, 0, 0);
                sf[nt] = MFMA_BF16(ql[kc], kbh, sf[nt], 0, 0, 0);
                sf[nt] = MFMA_BF16(qh[kc], kbl, sf[nt], 0, 0, 0);
            }
        __builtin_amdgcn_s_setprio(0);

        // key-padding mask
        #pragma unroll
        for (int nt = 0; nt < 4; nt++) {
            int mk = mask[b * S + k0 + nt*16 + l15];
            #pragma unroll
            for (int r = 0; r < 4; r++)
                sf[nt][r] = mk ? sf[nt][r] : -1e30f;
        }

        // online softmax (16 lanes per row) with exact rescale-skip
        unsigned short* Pu = (unsigned short*)&Ps[0][0];   // pitch 72 u16
        #pragma unroll
        for (int r = 0; r < 4; r++) {
            float pm = fmaxf(fmaxf(sf[0][r], sf[1][r]), fmaxf(sf[2][r], sf[3][r]));
            #pragma unroll
            for (int d = 1; d < 16; d <<= 1) pm = fmaxf(pm, __shfl_xor(pm, d, 16));
            bool anyNew = __any(pm > mrow[r]);
            float mn = fmaxf(mrow[r], pm);
            float p[4], rs = 0.f;
            #pragma unroll
            for (int nt = 0; nt < 4; nt++) { p[nt] = __expf(sf[nt][r] - mn); rs += p[nt]; }
            #pragma unroll
            for (int d = 1; d < 16; d <<= 1) rs += __shfl_xor(rs, d, 16);
            if (anyNew) {
                float corr = __expf(mrow[r] - mn);
                mrow[r] = mn;
                lrow[r] = lrow[r] * corr + rs;
                #pragma unroll
                for (int nt = 0; nt < 4; nt++) o[nt][r] *= corr;
            } else {
                lrow[r] += rs;
            }
            // swizzled P store: block c8 ^= (row>>1)&7
            int rowp = wid*16 + lg*4 + r;
            int xr   = (rowp >> 1) & 7;
            #pragma unroll
            for (int nt = 0; nt < 4; nt++) {
                int c8 = nt*2 + (l15 >> 3);
                _Float16 pv = (_Float16)p[nt];
                Pu[rowp * 72 + ((c8 ^ xr) * 8) + (l15 & 7)] =
                    *(unsigned short*)&pv;
            }
        }

        // wave-local RAW fence (Ps rows are wave-private); pin MFMA after it
        asm volatile("s_waitcnt lgkmcnt(0)" ::: "memory");
        __builtin_amdgcn_sched_barrier(0);

        // O += P V  (f16 MFMA; both operands read through their swizzles)
        __builtin_amdgcn_s_setprio(1);
        const int xrr = (l15 >> 1) & 7;   // (rowR>>1)&7 for rowR = wid*16+l15
        #pragma unroll
        for (int kc = 0; kc < 2; kc++) {
            f16x8 pa = *(const f16x8*)&Ps[wid*16 + l15][((kc*4 + lg) ^ xrr) * 8];
            #pragma unroll
            for (int nt = 0; nt < 4; nt++) {
                int c8p = (kc*4 + lg) ^ (nt*2 + (l15 >> 3));
                f16x8 vb = *(const f16x8*)&Vt[nt*16 + l15][c8p*8];
                o[nt] = MFMA_F16(pa, vb, o[nt], 0, 0, 0);
            }
        }
        __builtin_amdgcn_s_setprio(0);
    }

    // ---- epilogue: normalize + split, bounce through Ps for coalesced 16B stores
    unsigned short* Pu = (unsigned short*)&Ps[0][0];
    float inv[4];
    #pragma unroll
    for (int r = 0; r < 4; r++) inv[r] = 1.0f / lrow[r];

    #pragma unroll
    for (int plane = 0; plane < 2; plane++) {
        __syncthreads();   // previous reads of Ps done
        #pragma unroll
        for (int r = 0; r < 4; r++)
            #pragma unroll
            for (int nt = 0; nt < 4; nt++) {
                float v = o[nt][r] * inv[r];
                __bf16 hh, ll; split_bf16(v, hh, ll);
                __bf16 sv = plane == 0 ? hh : ll;
                Pu[(wid*16 + lg*4 + r) * 72 + nt*16 + l15] =
                    *(unsigned short*)&sv;
            }
        __syncthreads();
        __bf16* dst = plane == 0 ? AOh : AOl;
        #pragma unroll
        for (int i = 0; i < 2; i++) {
            int u   = tid + 1024 * i;     // 0..2047
            int row = u >> 3, c8 = u & 7;
            bf16x8 v8;
            #pragma unroll
            for (int jj = 0; jj < 8; jj++) {
                unsigned short us = Pu[row * 72 + c8*8 + jj];
                v8[jj] = *(__bf16*)&us;
            }
            *(bf16x8*)(dst + base + (size_t)(q0 + row) * E + c8 * 8) = v8;
        }
    }
}

// ---------------------------------------------------------------------------
extern "C" void kernel_launch(void* const* d_in, const int* in_sizes, int n_in,
                              void* d_out, int out_size, void* d_ws, size_t ws_size,
                              hipStream_t stream)
{
    const float* x    = (const float*)d_in[0];
    const int*   mask = (const int*)  d_in[1];
    const float* Wq   = (const float*)d_in[2];
    const float* Wk   = (const float*)d_in[3];
    const float* Wv   = (const float*)d_in[4];
    const float* Wo   = (const float*)d_in[5];
    float* out = (float*)d_out;

    const int B = 4, S = 2048, E = 1024;
    const int M = B * S;                          // 8192
    const size_t SZ  = (size_t)M * E;
    const size_t WSZ = (size_t)E * E;
    const size_t PB  = SZ * sizeof(__bf16);       // 16 MB per plane

    __bf16* xhi = (__bf16*)d_out;                 // x planes live in d_out
    __bf16* xlo = xhi + SZ;

    char* ws = (char*)d_ws;
    __bf16*   qhi = (__bf16*)(ws);
    __bf16*   qlo = (__bf16*)(ws + PB);
    __bf16*   khi = (__bf16*)(ws + 2*PB);
    __bf16*   klo = (__bf16*)(ws + 3*PB);
    _Float16* vh  = (_Float16*)(ws + 4*PB);
    __bf16*   wh  = (__bf16*)(ws + 5*PB);
    __bf16*   wl  = (__bf16*)(ws + 5*PB + WSZ*sizeof(__bf16));

    const int n8x = (int)(SZ / 8);
    const int n8w = (int)(WSZ / 8);

    split_kernel<<<n8x/256, 256, 0, stream>>>(x, xhi, xlo, n8x);

    dim3 gg(M/128, E/128);
    dim3 tb(256);

    split_kernel<<<n8w/256, 256, 0, stream>>>(Wq, wh, wl, n8w);
    gemm_split<1><<<gg, tb, 0, stream>>>(xhi, xlo, wh, wl,
        nullptr, qhi, qlo, nullptr, M, E, E, 0.125f);   // exact 1/sqrt(64)

    split_kernel<<<n8w/256, 256, 0, stream>>>(Wk, wh, wl, n8w);
    gemm_split<1><<<gg, tb, 0, stream>>>(xhi, xlo, wh, wl,
        nullptr, khi, klo, nullptr, M, E, E, 1.0f);

    split_kernel<<<n8w/256, 256, 0, stream>>>(Wv, wh, wl, n8w);
    gemm_split<2><<<gg, tb, 0, stream>>>(xhi, xlo, wh, wl,
        nullptr, nullptr, nullptr, vh, M, E, E, 1.0f);

    split_kernel<<<n8w/256, 256, 0, stream>>>(Wo, wh, wl, n8w);  // before attn

    attn_mfma<<<dim3(512), dim3(1024), 0, stream>>>(qhi, qlo, khi, klo, vh, mask,
                                                    qhi, qlo);   // AO aliases Q

    gemm_split<0><<<gg, tb, 0, stream>>>(qhi, qlo, wh, wl,
        out, nullptr, nullptr, nullptr, M, E, E, 1.0f);
}